// Round 4
// baseline (1019.337 us; speedup 1.0000x reference)
//
#include <hip/hip_runtime.h>
#include <cstdint>
#include <cstddef>

// ---------------------------------------------------------------------------
// FullyDynamicSTGNN: GAT(128 nodes, T=64, B=32) -> 2-layer Transformer(d=2048)
// -> linear head.  Heavy GEMMs in bf16 MFMA (16x16x32), everything else fp32.
// R4: GAT stage-3 bf16 swizzled operands + batched chunk loads + packed adds;
//     attention fully MFMA (QK^T and PV); single GEMMs split-K=2 at 128x128
//     with combines folded into LN / a tiny relu-combine kernel.
// ---------------------------------------------------------------------------

typedef unsigned short u16;
typedef __bf16 bf16x8 __attribute__((ext_vector_type(8)));
typedef float f32x4 __attribute__((ext_vector_type(4)));
typedef float f32x2 __attribute__((ext_vector_type(2)));
typedef unsigned int u32x4 __attribute__((ext_vector_type(4)));
typedef float f32x4v __attribute__((ext_vector_type(4)));
typedef unsigned short u16x4 __attribute__((ext_vector_type(4)));

__device__ __forceinline__ u16 f2b(float f) {
  union { float f; unsigned u; } x; x.f = f;
  unsigned r = x.u + 0x7fffu + ((x.u >> 16) & 1u);   // RNE
  return (u16)(r >> 16);
}
__device__ __forceinline__ float b2f(u16 s) {
  union { unsigned u; float f; } x; x.u = ((unsigned)s) << 16;
  return x.f;
}
__device__ __forceinline__ float b2f_lo(unsigned q) {
  union { unsigned u; float f; } x; x.u = q << 16;
  return x.f;
}
__device__ __forceinline__ float b2f_hi(unsigned q) {
  union { unsigned u; float f; } x; x.u = q & 0xffff0000u;
  return x.f;
}

// async global->LDS, 16B per lane; lds dest must be wave-uniform base (+lane*16)
__device__ __forceinline__ void gload_lds16(const void* g, void* l) {
  __builtin_amdgcn_global_load_lds(
      (const __attribute__((address_space(1))) unsigned int*)g,
      (__attribute__((address_space(3))) unsigned int*)l, 16, 0, 0);
}

// ---------------------------------------------------------------------------
// GAT kernel: one 1024-thread block per (b,t) graph.
// e[i][j] = att . leaky_relu(xl[i]+xr[j], 0.2) ; lrelu = 0.6x + 0.4|x|
//         = 0.6(cl_i + cr_j) + 0.4 * sum_h sgn_h * |xl2[i,h] + xr2[j,h]|
// where xl2 = |att_h| * xl (bf16), sgn_h = sign(att_h).
// LDS layouts:
//   xl2b/xr2b bf16 [n][64], 16B chunks swizzled: chunk c at slot c^((n>>2)&7)
//   xlTb bf16 [h][i] p136 (unscaled; stage-5 MFMA B operand)
//   esbT bf16 [j][i] p136 (stage-3 out -> stage-4 exp -> stage-5 MFMA A)
//   aggb bf16 [j][h] p72
// ---------------------------------------------------------------------------
__global__ __launch_bounds__(1024) void gat_kernel(
    const float* __restrict__ X, const float* __restrict__ V_Adap,
    const int* __restrict__ class_idx,
    const float* __restrict__ Wl, const float* __restrict__ bl,
    const float* __restrict__ Wr, const float* __restrict__ br,
    const float* __restrict__ att, const float* __restrict__ gat_bias,
    const float* __restrict__ Wfc, const float* __restrict__ bfc,
    float* __restrict__ h_f32, u16* __restrict__ h_b16)
{
  const int bt = blockIdx.x;
  const int tid = threadIdx.x;

  __shared__ __align__(16) u16   xl2b[128 * 64];    // 16384
  __shared__ __align__(16) u16   xr2b[128 * 64];    // 16384
  __shared__ __align__(16) u16   xlTb[64 * 136];    // 17408
  __shared__ __align__(16) u16   esbT[128 * 136];   // 34816
  __shared__ __align__(16) u16   aggb[128 * 72];    // 18432
  __shared__ __align__(16) float WlT[64 * 20];      // 5120  [h][f]
  __shared__ __align__(16) float WrT[64 * 20];      // 5120
  __shared__ __align__(16) float WfcT[16 * 66];     // 4224  [s][h]
  __shared__ __align__(16) float sgns[64];
  __shared__ float aab[64], bls[64], brs[64], gbias[64], bfcs[16];
  __shared__ float cls[128], crs[128], inv_s[128];
  __shared__ float red[8 * 128];                    // 4096

  // --- stage 0: load weights ---
  {
    const int h = tid >> 4, f = tid & 15;
    WlT[h * 20 + f] = Wl[f * 64 + h];
    WrT[h * 20 + f] = Wr[f * 64 + h];
    WfcT[f * 66 + h] = Wfc[h * 16 + f];
  }
  if (tid < 64) {
    const float a = att[tid];
    aab[tid] = __builtin_fabsf(a);
    sgns[tid] = (a >= 0.f) ? 1.f : -1.f;
    bls[tid] = bl[tid]; brs[tid] = br[tid]; gbias[tid] = gat_bias[tid];
  }
  if (tid < 16) bfcs[tid] = bfc[tid];
  const int cidx = *class_idx;
  __syncthreads();

  // --- stage 1: xl = x@Wl+bl, xr = x@Wr+br ; store scaled bf16 (swizzled)
  //     and unscaled xlTb for aggregation ---
  {
    const int n = tid >> 3, hq = tid & 7;
    const int sw = (n >> 2) & 7;
    const float* xp = X + (size_t)bt * 2048 + n * 16;
    float xv[16];
    #pragma unroll
    for (int f4 = 0; f4 < 4; f4++) {
      f32x4v t4 = ((const f32x4v*)xp)[f4];
      xv[f4 * 4 + 0] = t4[0]; xv[f4 * 4 + 1] = t4[1];
      xv[f4 * 4 + 2] = t4[2]; xv[f4 * 4 + 3] = t4[3];
    }
    #pragma unroll
    for (int k = 0; k < 8; k++) {
      const int h = hq + 8 * k;
      float al = bls[h], ar = brs[h];
      #pragma unroll
      for (int f4 = 0; f4 < 4; f4++) {
        f32x4v wl = *(const f32x4v*)&WlT[h * 20 + f4 * 4];
        f32x4v wr = *(const f32x4v*)&WrT[h * 20 + f4 * 4];
        #pragma unroll
        for (int f = 0; f < 4; f++) {
          al = fmaf(xv[f4 * 4 + f], wl[f], al);
          ar = fmaf(xv[f4 * 4 + f], wr[f], ar);
        }
      }
      xlTb[h * 136 + n] = f2b(al);
      const float sc = aab[h];
      // h = 8k + hq -> chunk k, elem hq; chunk k stored at slot k^sw
      const int pos = n * 64 + ((k ^ sw) << 3) + hq;
      xl2b[pos] = f2b(al * sc);
      xr2b[pos] = f2b(ar * sc);
    }
  }
  __syncthreads();

  // --- stage 2: cl[n] = sum_h sgn_h * xl2[n,h]  (= att.xl), same for cr ---
  if (tid < 256) {
    const int n = tid & 127;
    const u16* src = (tid < 128) ? xl2b : xr2b;
    const int sw = (n >> 2) & 7;
    float s = 0.f;
    #pragma unroll
    for (int sl = 0; sl < 8; sl++) {
      const int c = sl ^ sw;
      u32x4 q = *(const u32x4*)&src[n * 64 + sl * 8];
      f32x4v g0 = *(const f32x4v*)&sgns[c * 8];
      f32x4v g1 = *(const f32x4v*)&sgns[c * 8 + 4];
      s += g0[0] * b2f_lo(q[0]) + g0[1] * b2f_hi(q[0])
         + g0[2] * b2f_lo(q[1]) + g0[3] * b2f_hi(q[1]);
      s += g1[0] * b2f_lo(q[2]) + g1[1] * b2f_hi(q[2])
         + g1[2] * b2f_lo(q[3]) + g1[3] * b2f_hi(q[3]);
    }
    if (tid < 128) cls[n] = s; else crs[n] = s;
  }
  __syncthreads();

  // --- stage 3: e[i][j] (4i x 4j per thread, 8-h chunked batched loads) ---
  {
    const int i0 = (tid >> 5) * 4, j0 = (tid & 31) * 4;
    const int swi = (i0 >> 2) & 7, swj = (j0 >> 2) & 7;
    float acc[4][4] = {};
    #pragma unroll 2
    for (int hc = 0; hc < 8; hc++) {
      u32x4 ua[4], ub[4];
      #pragma unroll
      for (int a = 0; a < 4; a++)
        ua[a] = *(const u32x4*)&xl2b[(i0 + a) * 64 + ((hc ^ swi) << 3)];
      #pragma unroll
      for (int b = 0; b < 4; b++)
        ub[b] = *(const u32x4*)&xr2b[(j0 + b) * 64 + ((hc ^ swj) << 3)];
      f32x4v g0 = *(const f32x4v*)&sgns[hc * 8];
      f32x4v g1 = *(const f32x4v*)&sgns[hc * 8 + 4];
      #pragma unroll
      for (int ep = 0; ep < 4; ep++) {
        const float s0 = (ep < 2) ? g0[(ep & 1) * 2]     : g1[(ep & 1) * 2];
        const float s1 = (ep < 2) ? g0[(ep & 1) * 2 + 1] : g1[(ep & 1) * 2 + 1];
        f32x2 xap[4], xbp[4];
        #pragma unroll
        for (int a = 0; a < 4; a++) {
          const unsigned q = ua[a][ep];
          xap[a] = (f32x2){b2f_lo(q), b2f_hi(q)};
        }
        #pragma unroll
        for (int b = 0; b < 4; b++) {
          const unsigned q = ub[b][ep];
          xbp[b] = (f32x2){b2f_lo(q), b2f_hi(q)};
        }
        #pragma unroll
        for (int a = 0; a < 4; a++)
          #pragma unroll
          for (int b = 0; b < 4; b++) {
            const f32x2 z = xap[a] + xbp[b];   // hopefully v_pk_add_f32
            acc[a][b] = fmaf(s0, __builtin_fabsf(z[0]), acc[a][b]);
            acc[a][b] = fmaf(s1, __builtin_fabsf(z[1]), acc[a][b]);
          }
      }
    }
    const float* Vc = V_Adap + (size_t)cidx * 16384;
    float vm[4][4];
    #pragma unroll
    for (int a = 0; a < 4; a++) {
      f32x4v vc = *(const f32x4v*)&Vc[(size_t)(i0 + a) * 128 + j0];
      #pragma unroll
      for (int b = 0; b < 4; b++) vm[a][b] = vc[b];
    }
    #pragma unroll
    for (int b = 0; b < 4; b++) {
      const int j = j0 + b;
      const float ej = 0.6f * crs[j];
      u16x4 pk;
      #pragma unroll
      for (int a = 0; a < 4; a++) {
        const int i = i0 + a;
        const float e = ej + 0.6f * cls[i] + 0.4f * acc[a][b];
        // sigmoid(v)/128 > 0.004  <=>  v > ln(0.512/0.488)
        const bool m = (vm[a][b] > 0.04800922f) || (i == j);
        pk[a] = f2b(m ? e : -1e9f);
      }
      *(u16x4*)&esbT[j * 136 + i0] = pk;
    }
  }
  __syncthreads();

  // --- stage 4: p = exp(e) in-place on esbT rows; row-sum -> inv_s ---
  {
    const int j = tid >> 3, c = tid & 7;
    u16* rp = &esbT[j * 136 + c * 16];
    float ps = 0.f;
    #pragma unroll
    for (int half = 0; half < 2; half++) {
      u32x4 q = *(u32x4*)(rp + half * 8);
      #pragma unroll
      for (int w2 = 0; w2 < 4; w2++) {
        const float p0 = __expf(b2f_lo(q[w2]));
        const float p1 = __expf(b2f_hi(q[w2]));
        ps += p0 + p1;
        q[w2] = (unsigned)f2b(p0) | ((unsigned)f2b(p1) << 16);
      }
      *(u32x4*)(rp + half * 8) = q;
    }
    red[c * 128 + j] = ps;
  }
  __syncthreads();
  if (tid < 128) {
    float s = 0.f;
    #pragma unroll
    for (int c = 0; c < 8; c++) s += red[c * 128 + tid];
    inv_s[tid] = 1.f / s;
  }
  __syncthreads();

  // --- stage 5: agg[j][h] = (1/s_j) sum_i p^T[j][i] xl[i][h]  via MFMA ---
  {
    const int w = tid >> 6, lane = tid & 63;
    const int lq = lane >> 4, lr = lane & 15;
    const int jt = w >> 1, ht0 = (w & 1) * 2;
    f32x4 acc2[2] = {};
    #pragma unroll
    for (int ks = 0; ks < 4; ks++) {
      const bf16x8 af = __builtin_bit_cast(bf16x8,
          *(const u32x4*)&esbT[(jt * 16 + lr) * 136 + ks * 32 + lq * 8]);
      #pragma unroll
      for (int t = 0; t < 2; t++) {
        const bf16x8 bfb = __builtin_bit_cast(bf16x8,
            *(const u32x4*)&xlTb[((ht0 + t) * 16 + lr) * 136 + ks * 32 + lq * 8]);
        acc2[t] = __builtin_amdgcn_mfma_f32_16x16x32_bf16(af, bfb, acc2[t], 0, 0, 0);
      }
    }
    #pragma unroll
    for (int t = 0; t < 2; t++) {
      const int h = (ht0 + t) * 16 + lr;
      const float gb = gbias[h];
      #pragma unroll
      for (int r = 0; r < 4; r++) {
        const int j = jt * 16 + lq * 4 + r;
        aggb[j * 72 + h] = f2b(acc2[t][r] * inv_s[j] + gb);
      }
    }
  }
  __syncthreads();

  // --- stage 6: out = agg @ Wfc + bfc -> h (fp32 + bf16) ---
  {
    const int j = tid >> 3, s0 = (tid & 7) * 2;
    float o0 = bfcs[s0], o1 = bfcs[s0 + 1];
    #pragma unroll
    for (int h8 = 0; h8 < 8; h8++) {
      u32x4 q = *(const u32x4*)&aggb[j * 72 + h8 * 8];
      #pragma unroll
      for (int w2 = 0; w2 < 4; w2++) {
        const int h = h8 * 8 + w2 * 2;
        const float a0 = b2f_lo(q[w2]);
        const float a1 = b2f_hi(q[w2]);
        o0 = fmaf(a0, WfcT[s0 * 66 + h], o0);
        o1 = fmaf(a0, WfcT[(s0 + 1) * 66 + h], o1);
        o0 = fmaf(a1, WfcT[s0 * 66 + h + 1], o0);
        o1 = fmaf(a1, WfcT[(s0 + 1) * 66 + h + 1], o1);
      }
    }
    const size_t off = (size_t)bt * 2048 + j * 16 + s0;
    h_f32[off] = o0; h_f32[off + 1] = o1;
    h_b16[off] = f2b(o0); h_b16[off + 1] = f2b(o1);
  }
}

// ---------------------------------------------------------------------------
// transpose + cast: src (2048 x 2048) fp32 row-major -> dst bf16 (dst[n][k] =
// src[k][n]).  Up to 3 matrices via blockIdx.z.
// ---------------------------------------------------------------------------
struct TransArgs {
  const float* s0; const float* s1; const float* s2;
  u16* d0; u16* d1; u16* d2;
};

__global__ __launch_bounds__(256) void transpose_cast(TransArgs p)
{
  const float* src = (blockIdx.z == 0) ? p.s0 : (blockIdx.z == 1) ? p.s1 : p.s2;
  u16* dst = (blockIdx.z == 0) ? p.d0 : (blockIdx.z == 1) ? p.d1 : p.d2;
  __shared__ u16 tile[64][66];
  const int k0 = blockIdx.y * 64, n0 = blockIdx.x * 64;
  const int tid = threadIdx.x;
  const int c = tid & 63, rb = tid >> 6;
  #pragma unroll
  for (int r = 0; r < 16; r++) {
    const int k = rb + r * 4;
    tile[k][c] = f2b(src[(size_t)(k0 + k) * 2048 + n0 + c]);
  }
  __syncthreads();
  #pragma unroll
  for (int r = 0; r < 16; r++) {
    const int n = rb + r * 4;
    dst[(size_t)(n0 + n) * 2048 + k0 + c] = tile[c][n];
  }
}

// ---------------------------------------------------------------------------
// bf16 MFMA GEMM, 128x128 tile: C[m][n] = sum_k A[m][k]*Bt[n][k] + bias[n]
// z-batched over 3 B/C sets (QKV).  MODE 1: bf16 out.
// ---------------------------------------------------------------------------
struct GemmArgs {
  const u16* A;
  const u16* Bt0; const u16* Bt1; const u16* Bt2;
  const float* b0; const float* b1; const float* b2;
  void* C0; void* C1; void* C2;
  int N; int K;
};

__global__ __launch_bounds__(256) void gemm_bt(GemmArgs g)
{
  const int z = blockIdx.z;
  const u16* Bt = (z == 0) ? g.Bt0 : (z == 1) ? g.Bt1 : g.Bt2;
  const float* bias = (z == 0) ? g.b0 : (z == 1) ? g.b1 : g.b2;
  void* C = (z == 0) ? g.C0 : (z == 1) ? g.C1 : g.C2;
  const int N = g.N, K = g.K;
  const int m0 = blockIdx.y * 128, n0 = blockIdx.x * 128;

  __shared__ __align__(16) u16 As[128 * 32];
  __shared__ __align__(16) u16 Bs[128 * 32];

  const int tid = threadIdx.x;
  const int lane = tid & 63, w = tid >> 6;
  const int srow = w * 16 + (lane >> 2);
  const int scol = (lane & 3) * 8;
  const u16* gA = g.A + (size_t)(m0 + srow) * K + scol;
  const u16* gB = Bt + (size_t)(n0 + srow) * K + scol;
  u16* lA0 = &As[(w * 16) * 32];
  u16* lA1 = &As[(64 + w * 16) * 32];
  u16* lB0 = &Bs[(w * 16) * 32];
  u16* lB1 = &Bs[(64 + w * 16) * 32];

  const int wm = (w >> 1) * 64, wn = (w & 1) * 64;
  const int lq = lane >> 4, lr = lane & 15;

  f32x4 acc[4][4] = {};

  for (int k0 = 0; k0 < K; k0 += 32) {
    gload_lds16(gA + k0, lA0);
    gload_lds16(gA + (size_t)64 * K + k0, lA1);
    gload_lds16(gB + k0, lB0);
    gload_lds16(gB + (size_t)64 * K + k0, lB1);
    __syncthreads();

    bf16x8 af[4], bf[4];
    #pragma unroll
    for (int i = 0; i < 4; i++) {
      af[i] = __builtin_bit_cast(bf16x8, *(const u32x4*)&As[(wm + i * 16 + lr) * 32 + lq * 8]);
      bf[i] = __builtin_bit_cast(bf16x8, *(const u32x4*)&Bs[(wn + i * 16 + lr) * 32 + lq * 8]);
    }
    #pragma unroll
    for (int mi = 0; mi < 4; mi++)
      #pragma unroll
      for (int ni = 0; ni < 4; ni++)
        acc[mi][ni] = __builtin_amdgcn_mfma_f32_16x16x32_bf16(af[mi], bf[ni], acc[mi][ni], 0, 0, 0);
    __syncthreads();
  }

  #pragma unroll
  for (int ni = 0; ni < 4; ni++) {
    const int col = n0 + wn + ni * 16 + lr;
    const float bv = bias[col];
    #pragma unroll
    for (int mi = 0; mi < 4; mi++) {
      #pragma unroll
      for (int r = 0; r < 4; r++) {
        const int row = m0 + wm + mi * 16 + lq * 4 + r;
        float v = acc[mi][ni][r] + bv;
        ((u16*)C)[(size_t)row * N + col] = f2b(v);
      }
    }
  }
}

// ---------------------------------------------------------------------------
// split-K GEMM: z in {0,1} computes K-half [z*1024, z*1024+1024), fp32 partial
// (no bias) into Cz.  grid (16,16,2) = 512 blocks -> 2/CU.
// ---------------------------------------------------------------------------
struct GemmKArgs {
  const u16* A; const u16* Bt;
  float* C0; float* C1;
  int N; int K;   // full K
};

__global__ __launch_bounds__(256) void gemm_splitk(GemmKArgs g)
{
  const int z = blockIdx.z;
  float* C = z ? g.C1 : g.C0;
  const int N = g.N, K = g.K, kbase = z * (K >> 1);
  const int m0 = blockIdx.y * 128, n0 = blockIdx.x * 128;

  __shared__ __align__(16) u16 As[128 * 32];
  __shared__ __align__(16) u16 Bs[128 * 32];

  const int tid = threadIdx.x;
  const int lane = tid & 63, w = tid >> 6;
  const int srow = w * 16 + (lane >> 2);
  const int scol = (lane & 3) * 8;
  const u16* gA = g.A + (size_t)(m0 + srow) * K + kbase + scol;
  const u16* gB = g.Bt + (size_t)(n0 + srow) * K + kbase + scol;
  u16* lA0 = &As[(w * 16) * 32];
  u16* lA1 = &As[(64 + w * 16) * 32];
  u16* lB0 = &Bs[(w * 16) * 32];
  u16* lB1 = &Bs[(64 + w * 16) * 32];

  const int wm = (w >> 1) * 64, wn = (w & 1) * 64;
  const int lq = lane >> 4, lr = lane & 15;

  f32x4 acc[4][4] = {};

  for (int k0 = 0; k0 < (K >> 1); k0 += 32) {
    gload_lds16(gA + k0, lA0);
    gload_lds16(gA + (size_t)64 * K + k0, lA1);
    gload_lds16(gB + k0, lB0);
    gload_lds16(gB + (size_t)64 * K + k0, lB1);
    __syncthreads();

    bf16x8 af[4], bf[4];
    #pragma unroll
    for (int i = 0; i < 4; i++) {
      af[i] = __builtin_bit_cast(bf16x8, *(const u32x4*)&As[(wm + i * 16 + lr) * 32 + lq * 8]);
      bf[i] = __builtin_bit_cast(bf16x8, *(const u32x4*)&Bs[(wn + i * 16 + lr) * 32 + lq * 8]);
    }
    #pragma unroll
    for (int mi = 0; mi < 4; mi++)
      #pragma unroll
      for (int ni = 0; ni < 4; ni++)
        acc[mi][ni] = __builtin_amdgcn_mfma_f32_16x16x32_bf16(af[mi], bf[ni], acc[mi][ni], 0, 0, 0);
    __syncthreads();
  }

  #pragma unroll
  for (int ni = 0; ni < 4; ni++) {
    const int col = n0 + wn + ni * 16 + lr;
    #pragma unroll
    for (int mi = 0; mi < 4; mi++) {
      #pragma unroll
      for (int r = 0; r < 4; r++) {
        const int row = m0 + wm + mi * 16 + lq * 4 + r;
        C[(size_t)row * N + col] = acc[mi][ni][r];
      }
    }
  }
}

// ---------------------------------------------------------------------------
// attention via MFMA: one 256-thread block per (head, batch).  S=64, DH=128.
// qsb/ksb bf16 rows (native A/B layouts); V transposed into vsT (swizzled);
// scores fp32 in LDS (overlaying qsb), p bf16 (overlaying ksb); softmax w/o
// max pass; 1/s folded into PV epilogue.
// ---------------------------------------------------------------------------
__global__ __launch_bounds__(256) void attn_kernel(
    const u16* __restrict__ Qb, const u16* __restrict__ Kb,
    const u16* __restrict__ Vb, u16* __restrict__ AOb)
{
  const int head = blockIdx.x, b = blockIdx.y;
  const int tid = threadIdx.x;
  const int lane = tid & 63, w = tid >> 6;
  const int lq = lane >> 4, lr = lane & 15;

  __shared__ __align__(16) char smA[2 * 64 * 136 * 2];  // qsb|ksb -> ssf|psb
  __shared__ __align__(16) u16 vsT[128 * 72];           // 18432
  __shared__ float sred[256], sinv[64];

  u16* qsb = (u16*)smA;
  u16* ksb = qsb + 64 * 136;
  const size_t base = ((size_t)b * 64) * 2048 + (size_t)head * 128;

  // --- staging: Q,K direct bf16 rows; V -> transposed (swizzled) ---
  for (int idx = tid; idx < 1024; idx += 256) {
    const int t = idx >> 4, c = idx & 15;
    const size_t gp = base + (size_t)t * 2048 + c * 8;
    u32x4 q4 = *(const u32x4*)(Qb + gp);
    u32x4 k4 = *(const u32x4*)(Kb + gp);
    u32x4 v4 = *(const u32x4*)(Vb + gp);
    *(u32x4*)&qsb[t * 136 + c * 8] = q4;
    *(u32x4*)&ksb[t * 136 + c * 8] = k4;
    const int tcc = t >> 3, t7 = t & 7;
    #pragma unroll
    for (int e = 0; e < 8; e++) {
      const int d = c * 8 + e;
      const unsigned q = v4[e >> 1];
      const u16 val = (e & 1) ? (u16)(q >> 16) : (u16)(q & 0xffffu);
      vsT[d * 72 + ((tcc ^ ((d >> 3) & 7)) << 3) + t7] = val;
    }
  }
  __syncthreads();

  // --- scores MFMA: wave w -> i-tile w, all 4 j-tiles, K=128 ---
  f32x4 sacc[4] = {};
  #pragma unroll
  for (int ks = 0; ks < 4; ks++) {
    const bf16x8 af = __builtin_bit_cast(bf16x8,
        *(const u32x4*)&qsb[(w * 16 + lr) * 136 + ks * 32 + lq * 8]);
    #pragma unroll
    for (int jt = 0; jt < 4; jt++) {
      const bf16x8 bfb = __builtin_bit_cast(bf16x8,
          *(const u32x4*)&ksb[(jt * 16 + lr) * 136 + ks * 32 + lq * 8]);
      sacc[jt] = __builtin_amdgcn_mfma_f32_16x16x32_bf16(af, bfb, sacc[jt], 0, 0, 0);
    }
  }
  __syncthreads();   // qsb/ksb dead; reuse as ssf/psb

  float* ssf = (float*)smA;                  // [64][68] fp32
  u16* psb = (u16*)smA + 64 * 136;           // [64][136] bf16
  {
    const float sc = 0.08838834764831845f;   // 1/sqrt(128)
    #pragma unroll
    for (int jt = 0; jt < 4; jt++)
      #pragma unroll
      for (int r = 0; r < 4; r++)
        ssf[(w * 16 + lq * 4 + r) * 68 + jt * 16 + lr] = sacc[jt][r] * sc;
  }
  __syncthreads();

  // --- p = exp(s) (no max pass; s is O(1)); row sums -> sinv ---
  {
    const int i = tid >> 2, c = tid & 3;
    float ps = 0.f;
    #pragma unroll
    for (int cc = 0; cc < 4; cc++) {
      f32x4v s4 = *(const f32x4v*)&ssf[i * 68 + c * 16 + cc * 4];
      float p0 = __expf(s4[0]), p1 = __expf(s4[1]);
      float p2 = __expf(s4[2]), p3 = __expf(s4[3]);
      ps += p0 + p1 + p2 + p3;
      u16x4 pk = {f2b(p0), f2b(p1), f2b(p2), f2b(p3)};
      *(u16x4*)&psb[i * 136 + c * 16 + cc * 4] = pk;
    }
    sred[tid] = ps;
  }
  __syncthreads();
  if (tid < 64)
    sinv[tid] = 1.f / (sred[tid * 4] + sred[tid * 4 + 1] + sred[tid * 4 + 2] + sred[tid * 4 + 3]);
  __syncthreads();

  // --- PV MFMA: wave w -> i-tile w, 8 d-tiles, K=64 ---
  {
    f32x4 oacc[8] = {};
    #pragma unroll
    for (int ks = 0; ks < 2; ks++) {
      const bf16x8 af = __builtin_bit_cast(bf16x8,
          *(const u32x4*)&psb[(w * 16 + lr) * 136 + ks * 32 + lq * 8]);
      #pragma unroll
      for (int dt = 0; dt < 8; dt++) {
        const int d = dt * 16 + lr;
        const bf16x8 bfb = __builtin_bit_cast(bf16x8,
            *(const u32x4*)&vsT[d * 72 + (((ks * 4 + lq) ^ ((d >> 3) & 7)) << 3)]);
        oacc[dt] = __builtin_amdgcn_mfma_f32_16x16x32_bf16(af, bfb, oacc[dt], 0, 0, 0);
      }
    }
    #pragma unroll
    for (int r = 0; r < 4; r++) {
      const int i = w * 16 + lq * 4 + r;
      const float inv = sinv[i];
      #pragma unroll
      for (int dt = 0; dt < 8; dt++)
        AOb[base + (size_t)i * 2048 + dt * 16 + lr] = f2b(oacc[dt][r] * inv);
    }
  }
}

// ---------------------------------------------------------------------------
// fused residual + split-K combine + bias + layernorm
// h = LN(hin + d0 + d1 + bias) ; writes fp32 + bf16
// ---------------------------------------------------------------------------
__global__ __launch_bounds__(256) void ln_kernel2(
    const float* __restrict__ hin, const float* __restrict__ d0,
    const float* __restrict__ d1, const float* __restrict__ bias,
    const float* __restrict__ gamma, const float* __restrict__ beta,
    float* __restrict__ hout, u16* __restrict__ bout_)
{
  const int token = blockIdx.x, tid = threadIdx.x;
  const size_t off = (size_t)token * 2048;
  __shared__ float red[8];
  float v[8];
  float s = 0.f;
  #pragma unroll
  for (int r = 0; r < 8; r++) {
    const int i = r * 256 + tid;
    v[r] = hin[off + i] + d0[off + i] + d1[off + i] + bias[i];
    s += v[r];
  }
  #pragma unroll
  for (int o = 32; o > 0; o >>= 1) s += __shfl_down(s, o, 64);
  if ((tid & 63) == 0) red[tid >> 6] = s;
  __syncthreads();
  const float mean = (red[0] + red[1] + red[2] + red[3]) * (1.f / 2048.f);
  float s2 = 0.f;
  #pragma unroll
  for (int r = 0; r < 8; r++) { const float d = v[r] - mean; s2 = fmaf(d, d, s2); }
  #pragma unroll
  for (int o = 32; o > 0; o >>= 1) s2 += __shfl_down(s2, o, 64);
  if ((tid & 63) == 0) red[4 + (tid >> 6)] = s2;
  __syncthreads();
  const float var = (red[4] + red[5] + red[6] + red[7]) * (1.f / 2048.f);
  const float rstd = rsqrtf(var + 1e-5f);
  #pragma unroll
  for (int r = 0; r < 8; r++) {
    const int i = r * 256 + tid;
    const float y = (v[r] - mean) * rstd * gamma[i] + beta[i];
    hout[off + i] = y;
    bout_[off + i] = f2b(y);
  }
}

// ---------------------------------------------------------------------------
// split-K combine + bias + relu + cast for FF1:  out = bf16(relu(d0+d1+b))
// ---------------------------------------------------------------------------
__global__ __launch_bounds__(256) void combine_relu(
    const float* __restrict__ d0, const float* __restrict__ d1,
    const float* __restrict__ bias, u16* __restrict__ out)
{
  const size_t idx = ((size_t)blockIdx.x * 256 + threadIdx.x) * 4;
  const int col = (int)(idx & 2047);
  f32x4v a = *(const f32x4v*)(d0 + idx);
  f32x4v c = *(const f32x4v*)(d1 + idx);
  f32x4v bv = *(const f32x4v*)(bias + col);
  u16x4 o;
  #pragma unroll
  for (int e = 0; e < 4; e++) o[e] = f2b(fmaxf(a[e] + c[e] + bv[e], 0.f));
  *(u16x4*)(out + idx) = o;
}

// ---------------------------------------------------------------------------
// head: out[b][o] = h[b, T-1, :] . Wout[:, o] + bout[o]
// ---------------------------------------------------------------------------
__global__ __launch_bounds__(256) void final_kernel(
    const float* __restrict__ h, const float* __restrict__ Wout,
    const float* __restrict__ bout, float* __restrict__ out)
{
  const int b = blockIdx.x, tid = threadIdx.x;
  __shared__ float row[2048];
  __shared__ float part[256];
  const float* hr = h + ((size_t)b * 64 + 63) * 2048;
  for (int i = tid; i < 2048; i += 256) row[i] = hr[i];
  __syncthreads();
  const int o = tid & 15, ch = tid >> 4;
  float s = 0.f;
  if (o < 10) {
    const int i0 = ch * 128;
    for (int i = i0; i < i0 + 128; i++) s = fmaf(row[i], Wout[(size_t)i * 10 + o], s);
  }
  part[tid] = s;
  __syncthreads();
  if (tid < 10) {
    float t = bout[tid];
    for (int c2 = 0; c2 < 16; c2++) t += part[c2 * 16 + tid];
    out[(size_t)b * 10 + tid] = t;
  }
}

// ---------------------------------------------------------------------------
extern "C" void kernel_launch(void* const* d_in, const int* in_sizes, int n_in,
                              void* d_out, int out_size, void* d_ws, size_t ws_size,
                              hipStream_t stream)
{
  const float* X        = (const float*)d_in[0];
  const float* V_Adap   = (const float*)d_in[1];
  const float* Wl       = (const float*)d_in[2];
  const float* bl       = (const float*)d_in[3];
  const float* Wr       = (const float*)d_in[4];
  const float* br       = (const float*)d_in[5];
  const float* att      = (const float*)d_in[6];
  const float* gat_bias = (const float*)d_in[7];
  const float* Wfc      = (const float*)d_in[8];
  const float* bfc      = (const float*)d_in[9];
  const float* Wq       = (const float*)d_in[10];
  const float* bq       = (const float*)d_in[11];
  const float* Wk       = (const float*)d_in[12];
  const float* bk       = (const float*)d_in[13];
  const float* Wv       = (const float*)d_in[14];
  const float* bv       = (const float*)d_in[15];
  const float* Wo       = (const float*)d_in[16];
  const float* bo       = (const float*)d_in[17];
  const float* ln1_g    = (const float*)d_in[18];
  const float* ln1_b    = (const float*)d_in[19];
  const float* W1       = (const float*)d_in[20];
  const float* b1       = (const float*)d_in[21];
  const float* W2       = (const float*)d_in[22];
  const float* b2       = (const float*)d_in[23];
  const float* ln2_g    = (const float*)d_in[24];
  const float* ln2_b    = (const float*)d_in[25];
  const float* WoutP    = (const float*)d_in[26];
  const float* boutP    = (const float*)d_in[27];
  const int*   class_idx = (const int*)d_in[28];

  char* ws = (char*)d_ws;
  const size_t MB = (size_t)1 << 20;
  float* h_f32 = (float*)(ws);               // 16 MB  (B*T, D) fp32
  u16*   h_b16 = (u16*)(ws + 16 * MB);       //  8 MB
  u16*   Qb    = (u16*)(ws + 24 * MB);       //  8 MB
  u16*   Kb    = (u16*)(ws + 32 * MB);       //  8 MB
  u16*   Vb    = (u16*)(ws + 40 * MB);       //  8 MB
  u16*   AOb   = (u16*)(ws + 48 * MB);       //  8 MB
  float* tmp0  = (float*)(ws + 56 * MB);     // 16 MB  split-K partial 0
  float* tmp1  = (float*)(ws + 24 * MB);     // 16 MB  partial 1 (reuses Qb+Kb,
                                             //        dead after attn)
  u16*   ff1b  = (u16*)(ws + 72 * MB);       //  8 MB
  u16*   Wt0   = (u16*)(ws + 80 * MB);       //  8 MB transposed bf16 weights
  u16*   Wt1   = (u16*)(ws + 88 * MB);       //  8 MB
  u16*   Wt2   = (u16*)(ws + 96 * MB);       //  8 MB   (total 104 MB)

  // 1. GAT over all (b,t) graphs -> h (fp32 + bf16)
  gat_kernel<<<2048, 1024, 0, stream>>>(X, V_Adap, class_idx, Wl, bl, Wr, br,
                                        att, gat_bias, Wfc, bfc, h_f32, h_b16);

  const size_t DD = 2048ull * 2048ull;
  for (int l = 0; l < 2; l++) {
    const size_t wofs = (size_t)l * DD;
    const size_t bofs = (size_t)l * 2048;

    // QKV (batched z=3, 768 blocks)
    transpose_cast<<<dim3(32, 32, 3), 256, 0, stream>>>(
        TransArgs{Wq + wofs, Wk + wofs, Wv + wofs, Wt0, Wt1, Wt2});
    gemm_bt<<<dim3(16, 16, 3), 256, 0, stream>>>(
        GemmArgs{h_b16, Wt0, Wt1, Wt2, bq + bofs, bk + bofs, bv + bofs,
                 Qb, Kb, Vb, 2048, 2048});

    attn_kernel<<<dim3(16, 32), 256, 0, stream>>>(Qb, Kb, Vb, AOb);

    // o / W1 / W2 transposed together (Wt0..2 free once QKV gemm is done)
    transpose_cast<<<dim3(32, 32, 3), 256, 0, stream>>>(
        TransArgs{Wo + wofs, W1 + wofs, W2 + wofs, Wt0, Wt1, Wt2});

    // out-proj: split-K=2 -> partials, combined inside LN (with bias bo)
    gemm_splitk<<<dim3(16, 16, 2), 256, 0, stream>>>(
        GemmKArgs{AOb, Wt0, tmp0, tmp1, 2048, 2048});
    ln_kernel2<<<2048, 256, 0, stream>>>(h_f32, tmp0, tmp1, bo + bofs,
                                         ln1_g + bofs, ln1_b + bofs,
                                         h_f32, h_b16);

    // FF1: split-K=2 -> combine+bias+relu -> bf16
    gemm_splitk<<<dim3(16, 16, 2), 256, 0, stream>>>(
        GemmKArgs{h_b16, Wt1, tmp0, tmp1, 2048, 2048});
    combine_relu<<<4096, 256, 0, stream>>>(tmp0, tmp1, b1 + bofs, ff1b);

    // FF2: split-K=2 -> partials, combined inside LN (with bias b2)
    gemm_splitk<<<dim3(16, 16, 2), 256, 0, stream>>>(
        GemmKArgs{ff1b, Wt2, tmp0, tmp1, 2048, 2048});
    ln_kernel2<<<2048, 256, 0, stream>>>(h_f32, tmp0, tmp1, b2 + bofs,
                                         ln2_g + bofs, ln2_b + bofs,
                                         h_f32, h_b16);
  }

  final_kernel<<<32, 256, 0, stream>>>(h_f32, WoutP, boutP, (float*)d_out);
}